// Round 1
// baseline (104.835 us; speedup 1.0000x reference)
//
#include <hip/hip_runtime.h>
#include <math.h>

// Problem constants (from reference): N=1024, H=16, D=64, M=64
#define NN 1024
#define HH 16
#define DD 64
#define MM 64
#define EPSF 1e-6f

// One block per (n,h) pair. 256 threads.
// Layout trick: thread t owns m-quad (t&15)*4 across d = (t>>4) + 16*i, i=0..3.
// float4 group index g = t + 256*i  ->  element offset g*4 = d*64 + mq, so
// consecutive threads touch consecutive float4s (fully coalesced), while each
// thread's V-partial stays on a fixed m-quad (cheap 16-way LDS reduction).
__global__ __launch_bounds__(256) void rla_kernel(
    const float* __restrict__ q,    // (N,H,D)
    const float* __restrict__ k,    // (N,H,D)
    const float* __restrict__ v,    // (N,H,M)
    const float* __restrict__ Si,   // (N,H,D,M)
    const float* __restrict__ Zi,   // (N,H,D)
    float* __restrict__ outV,       // (N,H,M)
    float* __restrict__ outSi,      // (N,H,D,M)
    float* __restrict__ outZi)      // (N,H,D)
{
    const int nh = blockIdx.x;
    const int t  = threadIdx.x;

    __shared__ float sQ[DD];
    __shared__ float sK[DD];
    __shared__ float sVal[MM];
    __shared__ float sZ;                 // broadcast 1/(Q.Zn + eps)
    __shared__ float sPart[16][MM];      // V partials: [d-group][m]

    const size_t base_d = (size_t)nh * DD;
    const size_t base_m = (size_t)nh * MM;
    const size_t base_s = (size_t)nh * DD * MM;

    // Stage per-(n,h) vectors; compute feature maps + Zi_new.
    if (t < DD) {
        float qv = q[base_d + t];
        float kv = k[base_d + t];
        // elu(x)+1 = x>0 ? x+1 : exp(x)
        float Qf = qv > 0.f ? qv + 1.f : expf(qv);
        float Kf = kv > 0.f ? kv + 1.f : expf(kv);
        float zn = Zi[base_d + t] + Kf;
        sQ[t] = Qf;
        sK[t] = Kf;
        sVal[t] = v[base_m + t];         // M == D == 64
        outZi[base_d + t] = zn;
        // Z-reduction: wave 0 (threads 0..63) holds Qf*zn per lane.
        float p = Qf * zn;
        #pragma unroll
        for (int off = 32; off > 0; off >>= 1)
            p += __shfl_xor(p, off, 64);
        if (t == 0) sZ = 1.f / (p + EPSF);
    }
    __syncthreads();

    const int mq = (t & 15) * 4;         // fixed m-quad for this thread
    const int d0 = t >> 4;               // base d-group

    const float4 vv = *(const float4*)&sVal[mq];
    float4 acc = make_float4(0.f, 0.f, 0.f, 0.f);

    #pragma unroll
    for (int i = 0; i < 4; ++i) {
        const int d = d0 + 16 * i;
        const size_t eo = base_s + (size_t)(t + 256 * i) * 4;
        const float4 s = *(const float4*)&Si[eo];
        const float Kf = sK[d];
        float4 sn;
        sn.x = s.x + Kf * vv.x;
        sn.y = s.y + Kf * vv.y;
        sn.z = s.z + Kf * vv.z;
        sn.w = s.w + Kf * vv.w;
        *(float4*)&outSi[eo] = sn;
        const float Qf = sQ[d];
        acc.x += Qf * sn.x;
        acc.y += Qf * sn.y;
        acc.z += Qf * sn.z;
        acc.w += Qf * sn.w;
    }

    *(float4*)&sPart[d0][mq] = acc;
    __syncthreads();

    // Final V reduction: threads 0..63, one m each. Read col t of sPart
    // (word addr = r*64 + t -> bank t%32, 2 lanes/bank = conflict-free).
    if (t < MM) {
        float sum = 0.f;
        #pragma unroll
        for (int r = 0; r < 16; ++r)
            sum += sPart[r][t];
        outV[base_m + t] = sZ * sum;
    }
}

extern "C" void kernel_launch(void* const* d_in, const int* in_sizes, int n_in,
                              void* d_out, int out_size, void* d_ws, size_t ws_size,
                              hipStream_t stream) {
    const float* q  = (const float*)d_in[0];   // query (N,H,D)
    const float* k  = (const float*)d_in[1];   // key   (N,H,D)
    const float* v  = (const float*)d_in[2];   // value (N,H,M)
    const float* Si = (const float*)d_in[3];   // Si    (N,H,D,M)
    const float* Zi = (const float*)d_in[4];   // Zi    (N,H,D)

    float* out = (float*)d_out;
    // Outputs concatenated flat in return order: V, Si_new, Zi_new
    float* outV  = out;                                    // N*H*M
    float* outSi = out + (size_t)NN * HH * MM;             // N*H*D*M
    float* outZi = outSi + (size_t)NN * HH * DD * MM;      // N*H*D

    dim3 grid(NN * HH);
    dim3 block(256);
    rla_kernel<<<grid, block, 0, stream>>>(q, k, v, Si, Zi, outV, outSi, outZi);
}

// Round 3
// 91.291 us; speedup vs baseline: 1.1484x; 1.1484x over previous
//
#include <hip/hip_runtime.h>
#include <math.h>

// Problem constants (from reference): N=1024, H=16, D=64, M=64
#define NN 1024
#define HH 16
#define DD 64
#define MM 64
#define EPSF 1e-6f

// clang-native vector type: __builtin_nontemporal_* requires a vector of
// scalars, not HIP's HIP_vector_type wrapper class.
typedef float f32x4 __attribute__((ext_vector_type(4)));

// One block per (n,h) pair. 256 threads.
// Thread t owns m-quad (t&15)*4 across d = (t>>4) + 16*i, i=0..3.
// float4 group index g = t + 256*i  ->  element offset g*4 = d*64 + mq:
// consecutive threads touch consecutive float4s (fully coalesced), while each
// thread's V-partial stays on a fixed m-quad (16-way LDS reduction, conflict-free).
//
// Structure: issue staging loads (q/k/v/Zi) FIRST, then prefetch all 4 Si
// float4s into registers, THEN do elu + Z-reduce + barrier. The bulk Si
// traffic starts one HBM latency earlier per block and staging doesn't wait
// on it (in-order vmcnt: staging loads issued before Si loads).
__global__ __launch_bounds__(256) void rla_kernel(
    const float* __restrict__ q,    // (N,H,D)
    const float* __restrict__ k,    // (N,H,D)
    const float* __restrict__ v,    // (N,H,M)
    const float* __restrict__ Si,   // (N,H,D,M)
    const float* __restrict__ Zi,   // (N,H,D)
    float* __restrict__ outV,       // (N,H,M)
    float* __restrict__ outSi,      // (N,H,D,M)
    float* __restrict__ outZi)      // (N,H,D)
{
    const int nh = blockIdx.x;
    const int t  = threadIdx.x;

    __shared__ float sQ[DD];
    __shared__ float sK[DD];
    __shared__ float sVal[MM];
    __shared__ float sZ;                 // broadcast 1/(Q.Zn + eps)
    __shared__ float sPart[16][MM];      // V partials: [d-group][m]

    const size_t base_d = (size_t)nh * DD;
    const size_t base_m = (size_t)nh * MM;
    const size_t base_s = (size_t)nh * DD * MM;

    // --- issue staging loads first (wave 0 only) ---
    float qv = 0.f, kv = 0.f, vlv = 0.f, ziv = 0.f;
    if (t < DD) {
        qv  = q[base_d + t];
        kv  = k[base_d + t];
        vlv = v[base_m + t];             // M == D == 64
        ziv = Zi[base_d + t];
    }

    // --- prefetch the bulk Si stream into registers (issued before barrier) ---
    f32x4 s[4];
    #pragma unroll
    for (int i = 0; i < 4; ++i) {
        const size_t eo = base_s + (size_t)(t + 256 * i) * 4;
        s[i] = __builtin_nontemporal_load((const f32x4*)&Si[eo]);
    }

    // --- staging compute: elu feature maps, Zi_new, Z scalar ---
    if (t < DD) {
        // elu(x)+1 = x>0 ? x+1 : exp(x)
        float Qf = qv > 0.f ? qv + 1.f : expf(qv);
        float Kf = kv > 0.f ? kv + 1.f : expf(kv);
        float zn = ziv + Kf;
        sQ[t] = Qf;
        sK[t] = Kf;
        sVal[t] = vlv;
        outZi[base_d + t] = zn;
        // Z-reduction across wave 0 (64 lanes)
        float p = Qf * zn;
        #pragma unroll
        for (int off = 32; off > 0; off >>= 1)
            p += __shfl_xor(p, off, 64);
        if (t == 0) sZ = 1.f / (p + EPSF);
    }
    __syncthreads();

    const int mq = (t & 15) * 4;         // fixed m-quad for this thread
    const int d0 = t >> 4;               // base d-group

    const f32x4 vv = *(const f32x4*)&sVal[mq];
    f32x4 acc = (f32x4)(0.f);

    #pragma unroll
    for (int i = 0; i < 4; ++i) {
        const int d = d0 + 16 * i;
        const size_t eo = base_s + (size_t)(t + 256 * i) * 4;
        const float Kf = sK[d];
        const f32x4 sn = s[i] + Kf * vv;
        __builtin_nontemporal_store(sn, (f32x4*)&outSi[eo]);
        const float Qf = sQ[d];
        acc += Qf * sn;
    }

    *(f32x4*)&sPart[d0][mq] = acc;
    __syncthreads();

    // Final V reduction: threads 0..63, one m each. Read col t of sPart
    // (word addr = r*64 + t -> bank t%32, 2 lanes/bank = conflict-free).
    if (t < MM) {
        float sum = 0.f;
        #pragma unroll
        for (int r = 0; r < 16; ++r)
            sum += sPart[r][t];
        outV[base_m + t] = sZ * sum;
    }
}

extern "C" void kernel_launch(void* const* d_in, const int* in_sizes, int n_in,
                              void* d_out, int out_size, void* d_ws, size_t ws_size,
                              hipStream_t stream) {
    const float* q  = (const float*)d_in[0];   // query (N,H,D)
    const float* k  = (const float*)d_in[1];   // key   (N,H,D)
    const float* v  = (const float*)d_in[2];   // value (N,H,M)
    const float* Si = (const float*)d_in[3];   // Si    (N,H,D,M)
    const float* Zi = (const float*)d_in[4];   // Zi    (N,H,D)

    float* out = (float*)d_out;
    // Outputs concatenated flat in return order: V, Si_new, Zi_new
    float* outV  = out;                                    // N*H*M
    float* outSi = out + (size_t)NN * HH * MM;             // N*H*D*M
    float* outZi = outSi + (size_t)NN * HH * DD * MM;      // N*H*D

    dim3 grid(NN * HH);
    dim3 block(256);
    rla_kernel<<<grid, block, 0, stream>>>(q, k, v, Si, Zi, outV, outSi, outZi);
}